// Round 9
// baseline (4014.342 us; speedup 1.0000x reference)
//
#include <hip/hip_runtime.h>
#include <hip/hip_bf16.h>
#include <stdint.h>

#define BATCH 8
#define NPTS  16384
#define DIMF  64
#define SPTS  1024
#define NSAMP 32
#define MTOT  (BATCH*SPTS*NSAMP)   // 262144
#define CELLS 512                  // 8x8x8 spatial grid for FPS pruning

__device__ __forceinline__ float bfu_lo(uint32_t u){ return __uint_as_float(u<<16); }
__device__ __forceinline__ float bfu_hi(uint32_t u){ return __uint_as_float(u & 0xffff0000u); }
__device__ __forceinline__ uint16_t f2bf(float f){
  __hip_bfloat16 h = __float2bfloat16(f);
  uint16_t u; __builtin_memcpy(&u, &h, 2); return u;
}

// ---------------- prep: transpose points (B,64,N)->(B,N,64) ----------------
__global__ __launch_bounds__(256) void transpose_kernel(const float* __restrict__ pts,
                                                        float* __restrict__ ptsT){
  __shared__ float tile[32][33];
  int b = blockIdx.z;
  int n0 = blockIdx.x*32, c0 = blockIdx.y*32;
  int tx = threadIdx.x & 31, ty = threadIdx.x >> 5;
  const float* src = pts + (size_t)b*DIMF*NPTS;
  float* dst = ptsT + (size_t)b*NPTS*DIMF;
#pragma unroll
  for (int j=0;j<4;j++)
    tile[ty+8*j][tx] = src[(size_t)(c0+ty+8*j)*NPTS + n0 + tx];
  __syncthreads();
#pragma unroll
  for (int j=0;j<4;j++)
    dst[(size_t)(n0+ty+8*j)*DIMF + c0 + tx] = tile[tx][ty+8*j];
}

__device__ __forceinline__ int cell_of(float x, float y, float z){
  int ix=(int)(x*8.0f); ix = ix<0?0:(ix>7?7:ix);
  int iy=(int)(y*8.0f); iy = iy<0?0:(iy>7?7:iy);
  int iz=(int)(z*8.0f); iz = iz<0?0:(iz>7?7:iz);
  return (ix<<6)|(iy<<3)|iz;
}

// ---------------- FPS: exact bucket-pruned, 1 block (1024 thr) per batch ----------------
// Counting-sort points into 512 cells (order-independent), keep dst in LDS.
// Per iter: cells whose conservative lower bound >= cell max are provably
// no-ops for every contained point (reference min/argmax unchanged) -> skip.
// Distance chain / first-max tie semantics identical to the verified kernel.
__global__ __launch_bounds__(1024) void fps_kernel(const float* __restrict__ xyz,
                                                   float* __restrict__ out0,
                                                   float* __restrict__ sxg,
                                                   float* __restrict__ syg,
                                                   float* __restrict__ szg,
                                                   int*   __restrict__ sidg){
  int b = blockIdx.x;
  const float* X = xyz + (size_t)b*3*NPTS;
  float* sx = sxg + b*NPTS;  float* sy = syg + b*NPTS;
  float* sz = szg + b*NPTS;  int*   sid = sidg + b*NPTS;
  int t = threadIdx.x;
  int lane = t & 63, wid = t >> 6;   // 16 waves

  __shared__ float dst_s[NPTS];      // 64 KB
  __shared__ int   hist[CELLS];
  __shared__ int   cstart[CELLS];
  __shared__ int   cursor[CELLS];
  __shared__ float cmaxv[CELLS];
  __shared__ int   cmaxk[CELLS];     // original index of cell max
  __shared__ float cwx[CELLS], cwy[CELLS], cwz[CELLS];
  __shared__ int   dlist[CELLS];
  __shared__ int   ndirty;
  __shared__ int   wsum[16];
  __shared__ float pv[16]; __shared__ int pk[16];

  // --- histogram ---
  if (t < CELLS) hist[t] = 0;
  __syncthreads();
#pragma unroll
  for (int k=0;k<16;k++){
    int n = t + (k<<10);
    atomicAdd(&hist[cell_of(X[n], X[NPTS+n], X[2*NPTS+n])], 1);
  }
  __syncthreads();
  // --- exclusive scan over 512 (waves 0..7) ---
  {
    int v = (t<CELLS)? hist[t] : 0;
    int inc = v;
#pragma unroll
    for (int off=1; off<64; off<<=1){
      int u = __shfl_up(inc, off);
      if (lane >= off) inc += u;
    }
    if (t<CELLS && lane==63) wsum[wid] = inc;
    __syncthreads();
    if (t==0){ int acc=0; for(int w=0;w<8;w++){ int x=wsum[w]; wsum[w]=acc; acc+=x; } }
    __syncthreads();
    if (t<CELLS){
      int ex = inc - v + wsum[wid];
      cstart[t]=ex; cursor[t]=ex; cmaxv[t]=1e10f; cmaxk[t]=0x3fff;
    }
  }
  __syncthreads();
  // --- scatter sorted copy to global scratch ---
#pragma unroll
  for (int k=0;k<16;k++){
    int n = t + (k<<10);
    float x=X[n], y=X[NPTS+n], z=X[2*NPTS+n];
    int c = cell_of(x,y,z);
    int pos = atomicAdd(&cursor[c],1);
    sx[pos]=x; sy[pos]=y; sz[pos]=z; sid[pos]=n;
  }
  for (int n=t; n<NPTS; n+=1024) dst_s[n]=1e10f;
  if (t==0) ndirty=0;
  __syncthreads();

  float cx=X[0], cy=X[NPTS], cz=X[2*NPTS];   // first centroid = original point 0
  float* o = out0 + (size_t)b*3*SPTS;
  for (int s=0;s<SPTS;s++){
    if (t==0){ o[s]=cx; o[SPTS+s]=cy; o[2*SPTS+s]=cz; }
    if (s==SPTS-1) break;
    // ---- Phase A: mark dirty cells (conservative point-to-box lower bound) ----
    if (t < CELLS){
      float lox = (t>>6)      * 0.125f;
      float loy = ((t>>3)&7)  * 0.125f;
      float loz = (t&7)       * 0.125f;
      float dxx = fmaxf(fmaxf(lox-cx, cx-(lox+0.125f)), 0.f);
      float dyy = fmaxf(fmaxf(loy-cy, cy-(loy+0.125f)), 0.f);
      float dzz = fmaxf(fmaxf(loz-cz, cz-(loz+0.125f)), 0.f);
      float lb  = dxx*dxx + dyy*dyy + dzz*dzz;
      float lbAdj = lb*(1.0f-4e-6f) - 4e-6f;      // safe margin >> f32 eval error
      if (lbAdj < cmaxv[t]){
        int p = atomicAdd(&ndirty,1);
        dlist[p] = t;
      }
    }
    __syncthreads();
    int nd = ndirty;
    // ---- Phase B: update dirty cells, recompute their (max, origidx, coords) ----
    for (int i=wid; i<nd; i+=16){
      int c  = dlist[i];
      int st = cstart[c];
      int en = (c==CELLS-1)? NPTS : cstart[c+1];
      float bv=-1.f; int bo=0x7fffffff; float bx=0.f, by=0.f, bz=0.f;
      for (int base=st; base<en; base+=64){
        int pos = base+lane;
        if (pos<en){
          float x=sx[pos], y=sy[pos], z=sz[pos];
          float od = dst_s[pos];
          float ddx=__fsub_rn(x,cx), ddy=__fsub_rn(y,cy), ddz=__fsub_rn(z,cz);
          float d = __fadd_rn(__fadd_rn(__fmul_rn(ddx,ddx),__fmul_rn(ddy,ddy)),
                              __fmul_rn(ddz,ddz));
          d = fminf(od, d);
          dst_s[pos] = d;
          int orig = sid[pos];
          if (d > bv || (d == bv && orig < bo)){ bv=d; bo=orig; bx=x; by=y; bz=z; }
        }
      }
#pragma unroll
      for (int off=1; off<64; off<<=1){
        float ov=__shfl_xor(bv,off); int oo=__shfl_xor(bo,off);
        float ox=__shfl_xor(bx,off), oy=__shfl_xor(by,off), oz=__shfl_xor(bz,off);
        if (ov>bv || (ov==bv && oo<bo)){ bv=ov; bo=oo; bx=ox; by=oy; bz=oz; }
      }
      if (lane==0){ cmaxv[c]=bv; cmaxk[c]=bo; cwx[c]=bx; cwy[c]=by; cwz[c]=bz; }
    }
    __syncthreads();
    // ---- Phase C: argmax over 512 cell maxima (2-value shfl chain) ----
    {
      float v; int key;
      if (t < CELLS){ v = cmaxv[t]; key = ((cmaxk[t]&0x3fff)<<9) | t; }
      else          { v = -2.f;     key = 0x7fffffff; }
#pragma unroll
      for (int off=1; off<64; off<<=1){
        float ov=__shfl_xor(v,off); int ok=__shfl_xor(key,off);
        if (ov>v || (ov==v && ok<key)){ v=ov; key=ok; }
      }
      if (lane==0){ pv[wid]=v; pk[wid]=key; }
      if (t==0) ndirty = 0;                       // reset for next iter (pre-barrier)
      __syncthreads();
      v = pv[lane&15]; key = pk[lane&15];
#pragma unroll
      for (int off=1; off<16; off<<=1){
        float ov=__shfl_xor(v,off); int ok=__shfl_xor(key,off);
        if (ov>v || (ov==v && ok<key)){ v=ov; key=ok; }
      }
      int cell = key & 511;
      cx = cwx[cell]; cy = cwy[cell]; cz = cwz[cell];   // uniform across block
    }
  }
}

// ---------------- ball query: XLA-CPU f32 replication ----------------
// A (query norm), B (point norm): plain sequential ((x^2+y^2)+z^2)  [XLA reduce, no FMA]
// C (dot): Eigen gemm FMA chain fma(z*nz, fma(y*ny, x*nx))          [einsum -> Eigen]
// sqr = (A+B) - 2*C  (x2 exact, fuse-independent)
__global__ __launch_bounds__(256) void ball_kernel(const float* __restrict__ xyz,
                                                   const float* __restrict__ newxyz,
                                                   int* __restrict__ idxo){
  int b  = blockIdx.x >> 5;
  int sc = blockIdx.x & 31;           // 32 s per block
  const float* X  = xyz + (size_t)b*3*NPTS;
  int t = threadIdx.x, lane = t & 63, w = t >> 6;
  __shared__ float lx[512], ly[512], lz[512], ls[512];
  __shared__ int done;
  if (t==0) done = 0;
  const float rsq = 0.01f;
  float nx[8], ny[8], nz[8], sn[8];
  int cnt[8], first[8];
  int sbase = sc*32 + w*8;
#pragma unroll
  for (int q=0;q<8;q++){
    int s = sbase + q;
    nx[q] = newxyz[(size_t)b*3*SPTS + s];
    ny[q] = newxyz[(size_t)b*3*SPTS + SPTS + s];
    nz[q] = newxyz[(size_t)b*3*SPTS + 2*SPTS + s];
    sn[q] = __fadd_rn(__fadd_rn(__fmul_rn(nx[q],nx[q]),__fmul_rn(ny[q],ny[q])),
                      __fmul_rn(nz[q],nz[q]));
    cnt[q]=0; first[q]=0;
  }
  __syncthreads();
  for (int T=0;T<32;T++){
    {
      float ax = X[T*512 + t], ay = X[NPTS + T*512 + t], az = X[2*NPTS + T*512 + t];
      lx[t]=ax; ly[t]=ay; lz[t]=az;
      ls[t] = __fadd_rn(__fadd_rn(__fmul_rn(ax,ax),__fmul_rn(ay,ay)),__fmul_rn(az,az));
      float bx = X[T*512 + t + 256], by = X[NPTS + T*512 + t + 256], bz = X[2*NPTS + T*512 + t + 256];
      lx[t+256]=bx; ly[t+256]=by; lz[t+256]=bz;
      ls[t+256] = __fadd_rn(__fadd_rn(__fmul_rn(bx,bx),__fmul_rn(by,by)),__fmul_rn(bz,bz));
    }
    __syncthreads();
#pragma unroll
    for (int q=0;q<8;q++){
      if (cnt[q] >= NSAMP) continue;
      int s = sbase + q;
      int* op = idxo + ((size_t)(b*SPTS + s))*NSAMP;
      for (int c=0;c<8;c++){
        int li = c*64 + lane;
        float dot = fmaf(nz[q], lz[li], fmaf(ny[q], ly[li], __fmul_rn(nx[q], lx[li])));
        float sq  = __fsub_rn(__fadd_rn(sn[q], ls[li]), __fmul_rn(2.0f, dot));
        bool in = (sq <= rsq);
        unsigned long long m = __ballot(in);
        if (cnt[q]==0 && m) first[q] = T*512 + c*64 + (int)__builtin_ctzll(m);
        if (in){
          int slot = cnt[q] + (int)__popcll(m & ((1ull<<lane)-1ull));
          if (slot < NSAMP) op[slot] = T*512 + li;
        }
        cnt[q] += (int)__popcll(m);
        if (cnt[q] >= NSAMP){ if (lane==0) atomicAdd(&done,1); break; }
      }
    }
    __syncthreads();
    if (done >= 32) break;   // uniform across the block
  }
#pragma unroll
  for (int q=0;q<8;q++){
    if (cnt[q] < NSAMP){
      int s = sbase + q;
      int* op = idxo + ((size_t)(b*SPTS + s))*NSAMP;
      if (lane >= cnt[q] && lane < NSAMP) op[lane] = first[q];
    }
  }
}

// ---------------- GEMM1: fused gather (xyz diff + pts) x w1 -> y1 (bf16) ----------------
__global__ __launch_bounds__(256) void gemm1_kernel(const float* __restrict__ xyz,
                                                    const float* __restrict__ ptsT,
                                                    const int* __restrict__ idx,
                                                    const float* __restrict__ newxyz,
                                                    const float* __restrict__ w1,
                                                    const float* __restrict__ b1,
                                                    uint16_t* __restrict__ y1){
  __shared__ float As[128*69];
  __shared__ float Ws[67*64];
  __shared__ float bias[64];
  __shared__ int   ndx[128];
  __shared__ float nxs[4][3];
  int t = threadIdx.x;
  int g0 = blockIdx.x*128;
  if (t < 128) ndx[t] = idx[g0 + t];
  if (t < 12){
    int grp = t/3, c = t%3;
    int bs = (g0>>5) + grp; int b = bs>>10, s = bs & 1023;
    nxs[grp][c] = newxyz[(size_t)b*3*SPTS + c*SPTS + s];
  }
  if (t < 64) bias[t] = b1[t];
  for (int e=t; e<67*64; e+=256){ int k=e>>6, c=e&63; Ws[k*64+c] = w1[c*67+k]; }
  __syncthreads();
  {
    int r = t>>1, h = t&1;
    int n = ndx[r];
    int bs = (g0>>5) + (r>>5); int b = bs>>10;
    const float* pr = ptsT + ((size_t)(b*NPTS + n))*64 + h*32;
    float* ar = As + r*69;
    if (h==0){
      int grp = r>>5;
      ar[0] = __fsub_rn(xyz[(size_t)b*3*NPTS + n],          nxs[grp][0]);
      ar[1] = __fsub_rn(xyz[(size_t)b*3*NPTS + NPTS + n],   nxs[grp][1]);
      ar[2] = __fsub_rn(xyz[(size_t)b*3*NPTS + 2*NPTS + n], nxs[grp][2]);
    }
    float* ap = ar + 3 + h*32;
#pragma unroll
    for (int j=0;j<8;j++){
      float4 v = *(const float4*)(pr + j*4);
      ap[j*4+0]=v.x; ap[j*4+1]=v.y; ap[j*4+2]=v.z; ap[j*4+3]=v.w;
    }
  }
  __syncthreads();
  int rg = t>>3, cg = t&7;
  float acc[4][8];
#pragma unroll
  for (int i=0;i<4;i++)
#pragma unroll
    for (int j=0;j<8;j++) acc[i][j]=0.f;
  for (int k=0;k<67;k++){
    float a0 = As[(rg*4+0)*69+k];
    float a1 = As[(rg*4+1)*69+k];
    float a2 = As[(rg*4+2)*69+k];
    float a3 = As[(rg*4+3)*69+k];
    const float* wr = Ws + k*64 + cg*8;
    float4 w0 = *(const float4*)wr;
    float4 w1v = *(const float4*)(wr+4);
    float wj[8] = {w0.x,w0.y,w0.z,w0.w,w1v.x,w1v.y,w1v.z,w1v.w};
#pragma unroll
    for (int j=0;j<8;j++){
      acc[0][j] = fmaf(a0, wj[j], acc[0][j]);
      acc[1][j] = fmaf(a1, wj[j], acc[1][j]);
      acc[2][j] = fmaf(a2, wj[j], acc[2][j]);
      acc[3][j] = fmaf(a3, wj[j], acc[3][j]);
    }
  }
#pragma unroll
  for (int i=0;i<4;i++){
    int gr = g0 + rg*4 + i;
    uint16_t* yr = y1 + (size_t)gr*64 + cg*8;
    uint4 vv;
    uint32_t u[4];
#pragma unroll
    for (int j=0;j<4;j++){
      float v0 = acc[i][2*j]   + bias[cg*8+2*j];
      float v1 = acc[i][2*j+1] + bias[cg*8+2*j+1];
      u[j] = (uint32_t)f2bf(v0) | ((uint32_t)f2bf(v1)<<16);
    }
    vv.x=u[0]; vv.y=u[1]; vv.z=u[2]; vv.w=u[3];
    *(uint4*)yr = vv;
  }
}

// ---------------- GEMM2: relu(bn(y1)) x w2 -> y2 (bf16), K=64 ----------------
__global__ __launch_bounds__(256) void gemm2_kernel(const uint16_t* __restrict__ yin,
                                                    const float* __restrict__ w2,
                                                    const float* __restrict__ b2,
                                                    const float* __restrict__ scale,
                                                    const float* __restrict__ shift,
                                                    uint16_t* __restrict__ yout){
  __shared__ float As[128*65];
  __shared__ float Ws[64*64];
  __shared__ float bias[64], sc[64], sh[64];
  int t = threadIdx.x;
  int g0 = blockIdx.x*128;
  if (t < 64){ bias[t]=b2[t]; sc[t]=scale[t]; sh[t]=shift[t]; }
  for (int e=t; e<64*64; e+=256){ int k=e>>6, c=e&63; Ws[k*64+c] = w2[c*64+k]; }
  __syncthreads();
  {
    int r = t>>1, h = t&1;
    const uint4* yv = (const uint4*)(yin + (size_t)(g0+r)*64 + h*32);
    float* ar = As + r*65 + h*32;
#pragma unroll
    for (int j=0;j<4;j++){
      uint4 u = yv[j];
      uint32_t vv[4] = {u.x,u.y,u.z,u.w};
#pragma unroll
      for (int m=0;m<4;m++){
        int c = h*32 + j*8 + m*2;
        ar[j*8+m*2]   = fmaxf(fmaf(bfu_lo(vv[m]), sc[c],   sh[c]),   0.f);
        ar[j*8+m*2+1] = fmaxf(fmaf(bfu_hi(vv[m]), sc[c+1], sh[c+1]), 0.f);
      }
    }
  }
  __syncthreads();
  int rg = t>>3, cg = t&7;
  float acc[4][8];
#pragma unroll
  for (int i=0;i<4;i++)
#pragma unroll
    for (int j=0;j<8;j++) acc[i][j]=0.f;
  for (int k=0;k<64;k++){
    float a0 = As[(rg*4+0)*65+k];
    float a1 = As[(rg*4+1)*65+k];
    float a2 = As[(rg*4+2)*65+k];
    float a3 = As[(rg*4+3)*65+k];
    const float* wr = Ws + k*64 + cg*8;
    float4 w0 = *(const float4*)wr;
    float4 w1v = *(const float4*)(wr+4);
    float wj[8] = {w0.x,w0.y,w0.z,w0.w,w1v.x,w1v.y,w1v.z,w1v.w};
#pragma unroll
    for (int j=0;j<8;j++){
      acc[0][j] = fmaf(a0, wj[j], acc[0][j]);
      acc[1][j] = fmaf(a1, wj[j], acc[1][j]);
      acc[2][j] = fmaf(a2, wj[j], acc[2][j]);
      acc[3][j] = fmaf(a3, wj[j], acc[3][j]);
    }
  }
#pragma unroll
  for (int i=0;i<4;i++){
    int gr = g0 + rg*4 + i;
    uint16_t* yr = yout + (size_t)gr*64 + cg*8;
    uint4 vv; uint32_t u[4];
#pragma unroll
    for (int j=0;j<4;j++){
      float v0 = acc[i][2*j]   + bias[cg*8+2*j];
      float v1 = acc[i][2*j+1] + bias[cg*8+2*j+1];
      u[j] = (uint32_t)f2bf(v0) | ((uint32_t)f2bf(v1)<<16);
    }
    vv.x=u[0]; vv.y=u[1]; vv.z=u[2]; vv.w=u[3];
    *(uint4*)yr = vv;
  }
}

// ---------------- GEMM3: relu(bn(y2)) x w3 -> y3 (bf16), K=64, OUT=128 ----------------
__global__ __launch_bounds__(256) void gemm3_kernel(const uint16_t* __restrict__ yin,
                                                    const float* __restrict__ w3,
                                                    const float* __restrict__ b3,
                                                    const float* __restrict__ scale,
                                                    const float* __restrict__ shift,
                                                    uint16_t* __restrict__ yout){
  __shared__ float As[64*65];
  __shared__ float Ws[64*128];
  __shared__ float bias[128], sc[64], sh[64];
  int t = threadIdx.x;
  int g0 = blockIdx.x*64;
  if (t < 128) bias[t]=b3[t];
  if (t < 64){ sc[t]=scale[t]; sh[t]=shift[t]; }
  for (int e=t; e<64*128; e+=256){ int k=e>>7, c=e&127; Ws[k*128+c] = w3[c*64+k]; }
  __syncthreads();
  {
    int r = t>>2, h = t&3;
    const uint4* yv = (const uint4*)(yin + (size_t)(g0+r)*64 + h*16);
    float* ar = As + r*65 + h*16;
#pragma unroll
    for (int j=0;j<2;j++){
      uint4 u = yv[j];
      uint32_t vv[4] = {u.x,u.y,u.z,u.w};
#pragma unroll
      for (int m=0;m<4;m++){
        int c = h*16 + j*8 + m*2;
        ar[j*8+m*2]   = fmaxf(fmaf(bfu_lo(vv[m]), sc[c],   sh[c]),   0.f);
        ar[j*8+m*2+1] = fmaxf(fmaf(bfu_hi(vv[m]), sc[c+1], sh[c+1]), 0.f);
      }
    }
  }
  __syncthreads();
  int rg = t>>4, cg = t&15;
  float acc[4][8];
#pragma unroll
  for (int i=0;i<4;i++)
#pragma unroll
    for (int j=0;j<8;j++) acc[i][j]=0.f;
  for (int k=0;k<64;k++){
    float a0 = As[(rg*4+0)*65+k];
    float a1 = As[(rg*4+1)*65+k];
    float a2 = As[(rg*4+2)*65+k];
    float a3 = As[(rg*4+3)*65+k];
    const float* wr = Ws + k*128 + cg*8;
    float4 w0 = *(const float4*)wr;
    float4 w1v = *(const float4*)(wr+4);
    float wj[8] = {w0.x,w0.y,w0.z,w0.w,w1v.x,w1v.y,w1v.z,w1v.w};
#pragma unroll
    for (int j=0;j<8;j++){
      acc[0][j] = fmaf(a0, wj[j], acc[0][j]);
      acc[1][j] = fmaf(a1, wj[j], acc[1][j]);
      acc[2][j] = fmaf(a2, wj[j], acc[2][j]);
      acc[3][j] = fmaf(a3, wj[j], acc[3][j]);
    }
  }
#pragma unroll
  for (int i=0;i<4;i++){
    int gr = g0 + rg*4 + i;
    uint16_t* yr = yout + (size_t)gr*128 + cg*8;
    uint4 vv; uint32_t u[4];
#pragma unroll
    for (int j=0;j<4;j++){
      float v0 = acc[i][2*j]   + bias[cg*8+2*j];
      float v1 = acc[i][2*j+1] + bias[cg*8+2*j+1];
      u[j] = (uint32_t)f2bf(v0) | ((uint32_t)f2bf(v1)<<16);
    }
    vv.x=u[0]; vv.y=u[1]; vv.z=u[2]; vv.w=u[3];
    *(uint4*)yr = vv;
  }
}

// ---------------- per-channel stats (sum, sumsq) ----------------
template<int C>
__global__ __launch_bounds__(256) void stats_kernel(const uint16_t* __restrict__ y,
                                                    float* __restrict__ gsum,
                                                    float* __restrict__ gsq){
  constexpr int CP  = C/2;
  constexpr int RSL = 256/CP;
  int t = threadIdx.x;
  int c0 = t % CP, rs = t / CP;
  float s0=0.f,q0=0.f,s1=0.f,q1=0.f;
#pragma unroll 4
  for (int i=0;i<512/RSL;i++){
    int r = blockIdx.x*512 + rs + i*RSL;
    uint32_t u = *(const uint32_t*)(y + (size_t)r*C + 2*c0);
    float v0 = bfu_lo(u), v1 = bfu_hi(u);
    s0 += v0; q0 += v0*v0; s1 += v1; q1 += v1*v1;
  }
  __shared__ float red[4][256];
  red[0][t]=s0; red[1][t]=q0; red[2][t]=s1; red[3][t]=q1;
  __syncthreads();
  if (t < CP){
    float a0=0,a1=0,a2=0,a3=0;
    for (int k=0;k<RSL;k++){
      a0+=red[0][k*CP+t]; a1+=red[1][k*CP+t]; a2+=red[2][k*CP+t]; a3+=red[3][k*CP+t];
    }
    atomicAdd(&gsum[2*t],   a0); atomicAdd(&gsq[2*t],   a1);
    atomicAdd(&gsum[2*t+1], a2); atomicAdd(&gsq[2*t+1], a3);
  }
}

__global__ void finalize_kernel(const float* __restrict__ gsum, const float* __restrict__ gsq,
                                const float* __restrict__ g, const float* __restrict__ be,
                                float* __restrict__ scale, float* __restrict__ shift, int C){
  int c = threadIdx.x;
  if (c >= C) return;
  double mean = (double)gsum[c] / (double)MTOT;
  double var  = (double)gsq[c] / (double)MTOT - mean*mean;
  double s    = (double)g[c] / sqrt(var + 1e-5);
  scale[c] = (float)s;
  shift[c] = (float)((double)be[c] - mean*s);
}

// ---------------- bn3 + relu + maxpool over nsample + transpose ----------------
__global__ __launch_bounds__(256) void maxpool_kernel(const uint16_t* __restrict__ y3,
                                                      const float* __restrict__ scale,
                                                      const float* __restrict__ shift,
                                                      float* __restrict__ out1){
  __shared__ float tr[16][129];
  int t = threadIdx.x;
  int b = blockIdx.x >> 6;
  int s0 = (blockIdx.x & 63) * 16;
  int ch = t & 127, sl0 = t >> 7;
  float scv = scale[ch], shv = shift[ch];
  for (int sl=sl0; sl<16; sl+=2){
    int bs = b*SPTS + s0 + sl;
    const uint16_t* yr = y3 + (size_t)bs*NSAMP*128 + ch;
    float m = 0.0f;
#pragma unroll 4
    for (int k=0;k<NSAMP;k++){
      float v = __uint_as_float(((uint32_t)yr[k*128])<<16);
      float z = fmaxf(fmaf(v, scv, shv), 0.f);
      m = fmaxf(m, z);
    }
    tr[sl][ch] = m;
  }
  __syncthreads();
  int ch2 = t >> 1, hh = t & 1;
  float vals[8];
#pragma unroll
  for (int i=0;i<8;i++) vals[i] = tr[hh*8+i][ch2];
  float* op = out1 + (size_t)b*131072 + (size_t)ch2*1024 + s0 + hh*8;
  float4 v0; v0.x=vals[0]; v0.y=vals[1]; v0.z=vals[2]; v0.w=vals[3];
  float4 v1; v1.x=vals[4]; v1.y=vals[5]; v1.z=vals[6]; v1.w=vals[7];
  *(float4*)op = v0;
  *(float4*)(op+4) = v1;
}

extern "C" void kernel_launch(void* const* d_in, const int* in_sizes, int n_in,
                              void* d_out, int out_size, void* d_ws, size_t ws_size,
                              hipStream_t stream){
  (void)in_sizes; (void)n_in; (void)out_size; (void)ws_size;
  const float* xyz = (const float*)d_in[0];
  const float* pts = (const float*)d_in[1];
  const float* w1 = (const float*)d_in[2];  const float* b1 = (const float*)d_in[3];
  const float* g1 = (const float*)d_in[4];  const float* be1 = (const float*)d_in[5];
  const float* w2 = (const float*)d_in[6];  const float* b2 = (const float*)d_in[7];
  const float* g2 = (const float*)d_in[8];  const float* be2 = (const float*)d_in[9];
  const float* w3 = (const float*)d_in[10]; const float* b3 = (const float*)d_in[11];
  const float* g3 = (const float*)d_in[12]; const float* be3 = (const float*)d_in[13];

  float* out0 = (float*)d_out;                 // (B,3,1024)
  float* out1 = out0 + BATCH*3*SPTS;           // (B,128,1024)

  char* ws = (char*)d_ws;
  float*    ptsT = (float*)(ws + 0);                       // 33,554,432 B
  int*      idx  = (int*)  (ws + 34078720);                //  1,048,576 B
  uint16_t* y1   = (uint16_t*)(ws + 35127296);             // 33,554,432 B
  uint16_t* y2   = (uint16_t*)(ws + 68681728);             // 33,554,432 B
  uint16_t* y3   = (uint16_t*)(ws + 102236160);            // 67,108,864 B
  float*    stats = (float*)(ws + 169345024);              // 1536 floats
  // FPS sort scratch lives inside the y1 region (y1 is written only after fps/ball).
  float* sxg = (float*)(ws + 35127296);
  float* syg = (float*)(ws + 35127296 +   524288);
  float* szg = (float*)(ws + 35127296 + 2*524288);
  int*   sidg= (int*)  (ws + 35127296 + 3*524288);
  float* gsum1 = stats;        float* gsq1 = stats + 128;
  float* gsum2 = stats + 256;  float* gsq2 = stats + 384;
  float* gsum3 = stats + 512;  float* gsq3 = stats + 640;
  float* scale1 = stats + 768; float* shift1 = stats + 896;
  float* scale2 = stats + 1024; float* shift2 = stats + 1152;
  float* scale3 = stats + 1280; float* shift3 = stats + 1408;

  hipMemsetAsync(stats, 0, 768*sizeof(float), stream);

  transpose_kernel<<<dim3(NPTS/32, DIMF/32, BATCH), 256, 0, stream>>>(pts, ptsT);
  fps_kernel<<<BATCH, 1024, 0, stream>>>(xyz, out0, sxg, syg, szg, sidg);
  ball_kernel<<<BATCH*32, 256, 0, stream>>>(xyz, out0, idx);
  gemm1_kernel<<<MTOT/128, 256, 0, stream>>>(xyz, ptsT, idx, out0, w1, b1, y1);
  stats_kernel<64><<<512, 256, 0, stream>>>(y1, gsum1, gsq1);
  finalize_kernel<<<1, 128, 0, stream>>>(gsum1, gsq1, g1, be1, scale1, shift1, 64);
  gemm2_kernel<<<MTOT/128, 256, 0, stream>>>(y1, w2, b2, scale1, shift1, y2);
  stats_kernel<64><<<512, 256, 0, stream>>>(y2, gsum2, gsq2);
  finalize_kernel<<<1, 128, 0, stream>>>(gsum2, gsq2, g2, be2, scale2, shift2, 64);
  gemm3_kernel<<<MTOT/64, 256, 0, stream>>>(y2, w3, b3, scale2, shift2, y3);
  stats_kernel<128><<<512, 256, 0, stream>>>(y3, gsum3, gsq3);
  finalize_kernel<<<1, 128, 0, stream>>>(gsum3, gsq3, g3, be3, scale3, shift3, 128);
  maxpool_kernel<<<BATCH*(SPTS/16), 256, 0, stream>>>(y3, scale3, shift3, out1);
}

// Round 10
// 3225.347 us; speedup vs baseline: 1.2446x; 1.2446x over previous
//
#include <hip/hip_runtime.h>
#include <hip/hip_bf16.h>
#include <stdint.h>

#define BATCH 8
#define NPTS  16384
#define DIMF  64
#define SPTS  1024
#define NSAMP 32
#define MTOT  (BATCH*SPTS*NSAMP)   // 262144
#define CELLS 512                  // 8x8x8 spatial grid for FPS pruning

__device__ __forceinline__ float bfu_lo(uint32_t u){ return __uint_as_float(u<<16); }
__device__ __forceinline__ float bfu_hi(uint32_t u){ return __uint_as_float(u & 0xffff0000u); }
__device__ __forceinline__ uint16_t f2bf(float f){
  __hip_bfloat16 h = __float2bfloat16(f);
  uint16_t u; __builtin_memcpy(&u, &h, 2); return u;
}

__device__ __forceinline__ unsigned long long shfl_xor_u64(unsigned long long v, int off){
  unsigned lo = (unsigned)v, hi = (unsigned)(v>>32);
  lo = __shfl_xor(lo, off); hi = __shfl_xor(hi, off);
  return ((unsigned long long)hi<<32) | lo;
}

// ---------------- prep: transpose points (B,64,N)->(B,N,64) ----------------
__global__ __launch_bounds__(256) void transpose_kernel(const float* __restrict__ pts,
                                                        float* __restrict__ ptsT){
  __shared__ float tile[32][33];
  int b = blockIdx.z;
  int n0 = blockIdx.x*32, c0 = blockIdx.y*32;
  int tx = threadIdx.x & 31, ty = threadIdx.x >> 5;
  const float* src = pts + (size_t)b*DIMF*NPTS;
  float* dst = ptsT + (size_t)b*NPTS*DIMF;
#pragma unroll
  for (int j=0;j<4;j++)
    tile[ty+8*j][tx] = src[(size_t)(c0+ty+8*j)*NPTS + n0 + tx];
  __syncthreads();
#pragma unroll
  for (int j=0;j<4;j++)
    dst[(size_t)(n0+ty+8*j)*DIMF + c0 + tx] = tile[tx][ty+8*j];
}

__device__ __forceinline__ int cell_of(float x, float y, float z){
  int ix=(int)(x*8.0f); ix = ix<0?0:(ix>7?7:ix);
  int iy=(int)(y*8.0f); iy = iy<0?0:(iy>7?7:iy);
  int iz=(int)(z*8.0f); iz = iz<0?0:(iz>7?7:iz);
  return (ix<<6)|(iy<<3)|iz;
}

// ---------------- FPS: bucket-pruned, 1 barrier/iter, wave-owned cells ----------------
// Cell c is owned by wave w(c) = parity bits of (ix,iy,iz); each wave owns 64
// cells (1/lane). All per-cell state (cmaxv/cmaxk/cwx/dst ranges) is accessed
// ONLY by its owner wave -> wave-synchronous, no barrier. The only cross-wave
// traffic is the per-wave winner slot, parity-double-buffered (R5 pattern)
// around the single __syncthreads per iteration.
// Distance chain + first-max tie semantics bit-identical to verified kernels.
__global__ __launch_bounds__(512) void fps_kernel(const float* __restrict__ xyz,
                                                  float* __restrict__ out0,
                                                  float4* __restrict__ sortg){
  int b = blockIdx.x;
  const float* X = xyz + (size_t)b*3*NPTS;
  float4* sp = sortg + (size_t)b*NPTS;
  int t = threadIdx.x, lane = t & 63, w = t >> 6;   // 8 waves

  __shared__ float dst_s[NPTS];          // 64 KB
  __shared__ int   hist[CELLS];
  __shared__ int   cursor[CELLS];
  __shared__ int   cstart[CELLS+1];
  __shared__ float cmaxv[CELLS];
  __shared__ int   cmaxk[CELLS];
  __shared__ float cwx[CELLS], cwy[CELLS], cwz[CELLS];
  __shared__ int   wsum[8];
  __shared__ float4 pf4[2][8];
  __shared__ unsigned long long pk64[2][8];

  // --- histogram ---
  if (t < CELLS) hist[t] = 0;
  __syncthreads();
#pragma unroll
  for (int k=0;k<32;k++){
    int n = t + (k<<9);
    atomicAdd(&hist[cell_of(X[n],X[NPTS+n],X[2*NPTS+n])],1);
  }
  __syncthreads();
  // --- exclusive scan over 512 (block == 512 threads) ---
  {
    int v = hist[t], inc = v;
#pragma unroll
    for (int off=1; off<64; off<<=1){ int u=__shfl_up(inc,off); if(lane>=off) inc+=u; }
    if (lane==63) wsum[w] = inc;
    __syncthreads();
    if (t==0){ int acc=0; for(int i=0;i<8;i++){int x=wsum[i]; wsum[i]=acc; acc+=x;} }
    __syncthreads();
    int ex = inc - v + wsum[w];
    cstart[t]=ex; cursor[t]=ex;
    cmaxv[t] = (v>0)?1e10f:0.0f;
    cmaxk[t] = 16383;
    if (t==0) cstart[CELLS]=NPTS;
  }
  __syncthreads();
  // --- scatter sorted copy (x,y,z,orig) ---
#pragma unroll
  for (int k=0;k<32;k++){
    int n = t + (k<<9);
    float x=X[n], y=X[NPTS+n], z=X[2*NPTS+n];
    int c = cell_of(x,y,z);
    int pos = atomicAdd(&cursor[c],1);
    sp[pos] = make_float4(x,y,z,__int_as_float(n));
  }
  for (int n=t;n<NPTS;n+=512) dst_s[n]=1e10f;
  __syncthreads();

  // my cell: wave = parity bits, lane = high bits of (ix,iy,iz)
  int ix = (((lane>>5)&1)<<2) | (((lane>>4)&1)<<1) | ((w>>2)&1);
  int iy = (((lane>>3)&1)<<2) | (((lane>>2)&1)<<1) | ((w>>1)&1);
  int iz = (((lane>>1)&1)<<2) | (( lane    &1)<<1) | ( w    &1);
  int cm = (ix<<6)|(iy<<3)|iz;
  float lox=ix*0.125f, loy=iy*0.125f, loz=iz*0.125f;

  float cx=X[0], cy=X[NPTS], cz=X[2*NPTS];   // first centroid = point 0
  float* o = out0 + (size_t)b*3*SPTS;
  for (int s=0;s<SPTS;s++){
    if (t==0){ o[s]=cx; o[SPTS+s]=cy; o[2*SPTS+s]=cz; }
    if (s==SPTS-1) break;
    // ---- Phase A: per-lane lb test on own cell (no atomics) ----
    float dxx = fmaxf(fmaxf(lox-cx, cx-(lox+0.125f)),0.f);
    float dyy = fmaxf(fmaxf(loy-cy, cy-(loy+0.125f)),0.f);
    float dzz = fmaxf(fmaxf(loz-cz, cz-(loz+0.125f)),0.f);
    float lb = dxx*dxx+dyy*dyy+dzz*dzz;
    bool dirty = (lb*(1.0f-4e-6f)-4e-6f) < cmaxv[cm];   // margin validated in R9
    unsigned long long mask = __ballot(dirty);
    // ---- Phase B: wave processes its own dirty cells ----
    while (mask){
      int l = (int)__builtin_ctzll(mask); mask &= mask-1;
      int jx = (((l>>5)&1)<<2) | (((l>>4)&1)<<1) | ((w>>2)&1);
      int jy = (((l>>3)&1)<<2) | (((l>>2)&1)<<1) | ((w>>1)&1);
      int jz = (((l>>1)&1)<<2) | (( l    &1)<<1) | ( w    &1);
      int c = (jx<<6)|(jy<<3)|jz;
      int st = cstart[c], en = cstart[c+1];
      if (st >= en) continue;
      unsigned long long bp = 0ull; float bd=0.f,bx=0.f,by=0.f,bz=0.f;
      for (int base=st; base<en; base+=64){
        int pos = base+lane;
        if (pos<en){
          float4 pq = sp[pos];
          float ddx=__fsub_rn(pq.x,cx), ddy=__fsub_rn(pq.y,cy), ddz=__fsub_rn(pq.z,cz);
          float d = __fadd_rn(__fadd_rn(__fmul_rn(ddx,ddx),__fmul_rn(ddy,ddy)),
                              __fmul_rn(ddz,ddz));
          float od = dst_s[pos];
          d = fminf(od, d);
          dst_s[pos] = d;
          int orig = __float_as_int(pq.w);
          unsigned long long pk =
            ((unsigned long long)__float_as_uint(d)<<32) | (unsigned)(16383-orig);
          if (pk > bp){ bp=pk; bd=d; bx=pq.x; by=pq.y; bz=pq.z; }
        }
      }
      unsigned long long rp = bp;
#pragma unroll
      for (int off=1; off<64; off<<=1){
        unsigned long long op = shfl_xor_u64(rp, off);
        rp = (op>rp)? op : rp;
      }
      unsigned long long wm = __ballot(bp==rp);
      int wl = (int)__builtin_ctzll(wm);
      if (lane==wl){
        cmaxv[c]=bd;
        cmaxk[c]=16383-(int)(bp & 0xffffffffull);
        cwx[c]=bx; cwy[c]=by; cwz[c]=bz;
      }
    }
    __builtin_amdgcn_wave_barrier();
    // ---- Phase C: slice max over my wave's 64 cells (1/lane) ----
    int p = s & 1;
    {
      float v = cmaxv[cm]; int kk = cmaxk[cm];
      unsigned long long p2 =
        ((unsigned long long)__float_as_uint(v)<<32) | (unsigned)(16383-kk);
      unsigned long long r2 = p2;
#pragma unroll
      for (int off=1; off<64; off<<=1){
        unsigned long long o2 = shfl_xor_u64(r2, off);
        r2 = (o2>r2)? o2 : r2;
      }
      unsigned long long wm2 = __ballot(p2==r2);
      int wl2 = (int)__builtin_ctzll(wm2);
      if (lane==wl2){
        pf4[p][w] = make_float4(cwx[cm], cwy[cm], cwz[cm], 0.f);
        pk64[p][w] = r2;
      }
    }
    __syncthreads();
    {
      unsigned long long fv = pk64[p][lane&7], fr = fv;
#pragma unroll
      for (int off=1; off<8; off<<=1){
        unsigned long long of = shfl_xor_u64(fr, off);
        fr = (of>fr)? of : fr;
      }
      unsigned long long fm = __ballot(fv==fr);
      int fl = (int)__builtin_ctzll(fm) & 7;
      float4 cc = pf4[p][fl];
      cx=cc.x; cy=cc.y; cz=cc.z;     // uniform across block
    }
  }
}

// ---------------- ball query: XLA-CPU f32 replication ----------------
// A (query norm), B (point norm): plain sequential ((x^2+y^2)+z^2)  [XLA reduce, no FMA]
// C (dot): Eigen gemm FMA chain fma(z*nz, fma(y*ny, x*nx))          [einsum -> Eigen]
// sqr = (A+B) - 2*C  (x2 exact, fuse-independent)
__global__ __launch_bounds__(256) void ball_kernel(const float* __restrict__ xyz,
                                                   const float* __restrict__ newxyz,
                                                   int* __restrict__ idxo){
  int b  = blockIdx.x >> 5;
  int sc = blockIdx.x & 31;           // 32 s per block
  const float* X  = xyz + (size_t)b*3*NPTS;
  int t = threadIdx.x, lane = t & 63, w = t >> 6;
  __shared__ float lx[512], ly[512], lz[512], ls[512];
  __shared__ int done;
  if (t==0) done = 0;
  const float rsq = 0.01f;
  float nx[8], ny[8], nz[8], sn[8];
  int cnt[8], first[8];
  int sbase = sc*32 + w*8;
#pragma unroll
  for (int q=0;q<8;q++){
    int s = sbase + q;
    nx[q] = newxyz[(size_t)b*3*SPTS + s];
    ny[q] = newxyz[(size_t)b*3*SPTS + SPTS + s];
    nz[q] = newxyz[(size_t)b*3*SPTS + 2*SPTS + s];
    sn[q] = __fadd_rn(__fadd_rn(__fmul_rn(nx[q],nx[q]),__fmul_rn(ny[q],ny[q])),
                      __fmul_rn(nz[q],nz[q]));
    cnt[q]=0; first[q]=0;
  }
  __syncthreads();
  for (int T=0;T<32;T++){
    {
      float ax = X[T*512 + t], ay = X[NPTS + T*512 + t], az = X[2*NPTS + T*512 + t];
      lx[t]=ax; ly[t]=ay; lz[t]=az;
      ls[t] = __fadd_rn(__fadd_rn(__fmul_rn(ax,ax),__fmul_rn(ay,ay)),__fmul_rn(az,az));
      float bx = X[T*512 + t + 256], by = X[NPTS + T*512 + t + 256], bz = X[2*NPTS + T*512 + t + 256];
      lx[t+256]=bx; ly[t+256]=by; lz[t+256]=bz;
      ls[t+256] = __fadd_rn(__fadd_rn(__fmul_rn(bx,bx),__fmul_rn(by,by)),__fmul_rn(bz,bz));
    }
    __syncthreads();
#pragma unroll
    for (int q=0;q<8;q++){
      if (cnt[q] >= NSAMP) continue;
      int s = sbase + q;
      int* op = idxo + ((size_t)(b*SPTS + s))*NSAMP;
      for (int c=0;c<8;c++){
        int li = c*64 + lane;
        float dot = fmaf(nz[q], lz[li], fmaf(ny[q], ly[li], __fmul_rn(nx[q], lx[li])));
        float sq  = __fsub_rn(__fadd_rn(sn[q], ls[li]), __fmul_rn(2.0f, dot));
        bool in = (sq <= rsq);
        unsigned long long m = __ballot(in);
        if (cnt[q]==0 && m) first[q] = T*512 + c*64 + (int)__builtin_ctzll(m);
        if (in){
          int slot = cnt[q] + (int)__popcll(m & ((1ull<<lane)-1ull));
          if (slot < NSAMP) op[slot] = T*512 + li;
        }
        cnt[q] += (int)__popcll(m);
        if (cnt[q] >= NSAMP){ if (lane==0) atomicAdd(&done,1); break; }
      }
    }
    __syncthreads();
    if (done >= 32) break;   // uniform across the block
  }
#pragma unroll
  for (int q=0;q<8;q++){
    if (cnt[q] < NSAMP){
      int s = sbase + q;
      int* op = idxo + ((size_t)(b*SPTS + s))*NSAMP;
      if (lane >= cnt[q] && lane < NSAMP) op[lane] = first[q];
    }
  }
}

// ---------------- GEMM1: fused gather (xyz diff + pts) x w1 -> y1 (bf16) ----------------
__global__ __launch_bounds__(256) void gemm1_kernel(const float* __restrict__ xyz,
                                                    const float* __restrict__ ptsT,
                                                    const int* __restrict__ idx,
                                                    const float* __restrict__ newxyz,
                                                    const float* __restrict__ w1,
                                                    const float* __restrict__ b1,
                                                    uint16_t* __restrict__ y1){
  __shared__ float As[128*69];
  __shared__ float Ws[67*64];
  __shared__ float bias[64];
  __shared__ int   ndx[128];
  __shared__ float nxs[4][3];
  int t = threadIdx.x;
  int g0 = blockIdx.x*128;
  if (t < 128) ndx[t] = idx[g0 + t];
  if (t < 12){
    int grp = t/3, c = t%3;
    int bs = (g0>>5) + grp; int b = bs>>10, s = bs & 1023;
    nxs[grp][c] = newxyz[(size_t)b*3*SPTS + c*SPTS + s];
  }
  if (t < 64) bias[t] = b1[t];
  for (int e=t; e<67*64; e+=256){ int k=e>>6, c=e&63; Ws[k*64+c] = w1[c*67+k]; }
  __syncthreads();
  {
    int r = t>>1, h = t&1;
    int n = ndx[r];
    int bs = (g0>>5) + (r>>5); int b = bs>>10;
    const float* pr = ptsT + ((size_t)(b*NPTS + n))*64 + h*32;
    float* ar = As + r*69;
    if (h==0){
      int grp = r>>5;
      ar[0] = __fsub_rn(xyz[(size_t)b*3*NPTS + n],          nxs[grp][0]);
      ar[1] = __fsub_rn(xyz[(size_t)b*3*NPTS + NPTS + n],   nxs[grp][1]);
      ar[2] = __fsub_rn(xyz[(size_t)b*3*NPTS + 2*NPTS + n], nxs[grp][2]);
    }
    float* ap = ar + 3 + h*32;
#pragma unroll
    for (int j=0;j<8;j++){
      float4 v = *(const float4*)(pr + j*4);
      ap[j*4+0]=v.x; ap[j*4+1]=v.y; ap[j*4+2]=v.z; ap[j*4+3]=v.w;
    }
  }
  __syncthreads();
  int rg = t>>3, cg = t&7;
  float acc[4][8];
#pragma unroll
  for (int i=0;i<4;i++)
#pragma unroll
    for (int j=0;j<8;j++) acc[i][j]=0.f;
  for (int k=0;k<67;k++){
    float a0 = As[(rg*4+0)*69+k];
    float a1 = As[(rg*4+1)*69+k];
    float a2 = As[(rg*4+2)*69+k];
    float a3 = As[(rg*4+3)*69+k];
    const float* wr = Ws + k*64 + cg*8;
    float4 w0 = *(const float4*)wr;
    float4 w1v = *(const float4*)(wr+4);
    float wj[8] = {w0.x,w0.y,w0.z,w0.w,w1v.x,w1v.y,w1v.z,w1v.w};
#pragma unroll
    for (int j=0;j<8;j++){
      acc[0][j] = fmaf(a0, wj[j], acc[0][j]);
      acc[1][j] = fmaf(a1, wj[j], acc[1][j]);
      acc[2][j] = fmaf(a2, wj[j], acc[2][j]);
      acc[3][j] = fmaf(a3, wj[j], acc[3][j]);
    }
  }
#pragma unroll
  for (int i=0;i<4;i++){
    int gr = g0 + rg*4 + i;
    uint16_t* yr = y1 + (size_t)gr*64 + cg*8;
    uint4 vv;
    uint32_t u[4];
#pragma unroll
    for (int j=0;j<4;j++){
      float v0 = acc[i][2*j]   + bias[cg*8+2*j];
      float v1 = acc[i][2*j+1] + bias[cg*8+2*j+1];
      u[j] = (uint32_t)f2bf(v0) | ((uint32_t)f2bf(v1)<<16);
    }
    vv.x=u[0]; vv.y=u[1]; vv.z=u[2]; vv.w=u[3];
    *(uint4*)yr = vv;
  }
}

// ---------------- GEMM2: relu(bn(y1)) x w2 -> y2 (bf16), K=64 ----------------
__global__ __launch_bounds__(256) void gemm2_kernel(const uint16_t* __restrict__ yin,
                                                    const float* __restrict__ w2,
                                                    const float* __restrict__ b2,
                                                    const float* __restrict__ scale,
                                                    const float* __restrict__ shift,
                                                    uint16_t* __restrict__ yout){
  __shared__ float As[128*65];
  __shared__ float Ws[64*64];
  __shared__ float bias[64], sc[64], sh[64];
  int t = threadIdx.x;
  int g0 = blockIdx.x*128;
  if (t < 64){ bias[t]=b2[t]; sc[t]=scale[t]; sh[t]=shift[t]; }
  for (int e=t; e<64*64; e+=256){ int k=e>>6, c=e&63; Ws[k*64+c] = w2[c*64+k]; }
  __syncthreads();
  {
    int r = t>>1, h = t&1;
    const uint4* yv = (const uint4*)(yin + (size_t)(g0+r)*64 + h*32);
    float* ar = As + r*65 + h*32;
#pragma unroll
    for (int j=0;j<4;j++){
      uint4 u = yv[j];
      uint32_t vv[4] = {u.x,u.y,u.z,u.w};
#pragma unroll
      for (int m=0;m<4;m++){
        int c = h*32 + j*8 + m*2;
        ar[j*8+m*2]   = fmaxf(fmaf(bfu_lo(vv[m]), sc[c],   sh[c]),   0.f);
        ar[j*8+m*2+1] = fmaxf(fmaf(bfu_hi(vv[m]), sc[c+1], sh[c+1]), 0.f);
      }
    }
  }
  __syncthreads();
  int rg = t>>3, cg = t&7;
  float acc[4][8];
#pragma unroll
  for (int i=0;i<4;i++)
#pragma unroll
    for (int j=0;j<8;j++) acc[i][j]=0.f;
  for (int k=0;k<64;k++){
    float a0 = As[(rg*4+0)*65+k];
    float a1 = As[(rg*4+1)*65+k];
    float a2 = As[(rg*4+2)*65+k];
    float a3 = As[(rg*4+3)*65+k];
    const float* wr = Ws + k*64 + cg*8;
    float4 w0 = *(const float4*)wr;
    float4 w1v = *(const float4*)(wr+4);
    float wj[8] = {w0.x,w0.y,w0.z,w0.w,w1v.x,w1v.y,w1v.z,w1v.w};
#pragma unroll
    for (int j=0;j<8;j++){
      acc[0][j] = fmaf(a0, wj[j], acc[0][j]);
      acc[1][j] = fmaf(a1, wj[j], acc[1][j]);
      acc[2][j] = fmaf(a2, wj[j], acc[2][j]);
      acc[3][j] = fmaf(a3, wj[j], acc[3][j]);
    }
  }
#pragma unroll
  for (int i=0;i<4;i++){
    int gr = g0 + rg*4 + i;
    uint16_t* yr = yout + (size_t)gr*64 + cg*8;
    uint4 vv; uint32_t u[4];
#pragma unroll
    for (int j=0;j<4;j++){
      float v0 = acc[i][2*j]   + bias[cg*8+2*j];
      float v1 = acc[i][2*j+1] + bias[cg*8+2*j+1];
      u[j] = (uint32_t)f2bf(v0) | ((uint32_t)f2bf(v1)<<16);
    }
    vv.x=u[0]; vv.y=u[1]; vv.z=u[2]; vv.w=u[3];
    *(uint4*)yr = vv;
  }
}

// ---------------- GEMM3: relu(bn(y2)) x w3 -> y3 (bf16), K=64, OUT=128 ----------------
__global__ __launch_bounds__(256) void gemm3_kernel(const uint16_t* __restrict__ yin,
                                                    const float* __restrict__ w3,
                                                    const float* __restrict__ b3,
                                                    const float* __restrict__ scale,
                                                    const float* __restrict__ shift,
                                                    uint16_t* __restrict__ yout){
  __shared__ float As[64*65];
  __shared__ float Ws[64*128];
  __shared__ float bias[128], sc[64], sh[64];
  int t = threadIdx.x;
  int g0 = blockIdx.x*64;
  if (t < 128) bias[t]=b3[t];
  if (t < 64){ sc[t]=scale[t]; sh[t]=shift[t]; }
  for (int e=t; e<64*128; e+=256){ int k=e>>7, c=e&127; Ws[k*128+c] = w3[c*64+k]; }
  __syncthreads();
  {
    int r = t>>2, h = t&3;
    const uint4* yv = (const uint4*)(yin + (size_t)(g0+r)*64 + h*16);
    float* ar = As + r*65 + h*16;
#pragma unroll
    for (int j=0;j<2;j++){
      uint4 u = yv[j];
      uint32_t vv[4] = {u.x,u.y,u.z,u.w};
#pragma unroll
      for (int m=0;m<4;m++){
        int c = h*16 + j*8 + m*2;
        ar[j*8+m*2]   = fmaxf(fmaf(bfu_lo(vv[m]), sc[c],   sh[c]),   0.f);
        ar[j*8+m*2+1] = fmaxf(fmaf(bfu_hi(vv[m]), sc[c+1], sh[c+1]), 0.f);
      }
    }
  }
  __syncthreads();
  int rg = t>>4, cg = t&15;
  float acc[4][8];
#pragma unroll
  for (int i=0;i<4;i++)
#pragma unroll
    for (int j=0;j<8;j++) acc[i][j]=0.f;
  for (int k=0;k<64;k++){
    float a0 = As[(rg*4+0)*65+k];
    float a1 = As[(rg*4+1)*65+k];
    float a2 = As[(rg*4+2)*65+k];
    float a3 = As[(rg*4+3)*65+k];
    const float* wr = Ws + k*128 + cg*8;
    float4 w0 = *(const float4*)wr;
    float4 w1v = *(const float4*)(wr+4);
    float wj[8] = {w0.x,w0.y,w0.z,w0.w,w1v.x,w1v.y,w1v.z,w1v.w};
#pragma unroll
    for (int j=0;j<8;j++){
      acc[0][j] = fmaf(a0, wj[j], acc[0][j]);
      acc[1][j] = fmaf(a1, wj[j], acc[1][j]);
      acc[2][j] = fmaf(a2, wj[j], acc[2][j]);
      acc[3][j] = fmaf(a3, wj[j], acc[3][j]);
    }
  }
#pragma unroll
  for (int i=0;i<4;i++){
    int gr = g0 + rg*4 + i;
    uint16_t* yr = yout + (size_t)gr*128 + cg*8;
    uint4 vv; uint32_t u[4];
#pragma unroll
    for (int j=0;j<4;j++){
      float v0 = acc[i][2*j]   + bias[cg*8+2*j];
      float v1 = acc[i][2*j+1] + bias[cg*8+2*j+1];
      u[j] = (uint32_t)f2bf(v0) | ((uint32_t)f2bf(v1)<<16);
    }
    vv.x=u[0]; vv.y=u[1]; vv.z=u[2]; vv.w=u[3];
    *(uint4*)yr = vv;
  }
}

// ---------------- per-channel stats (sum, sumsq) ----------------
template<int C>
__global__ __launch_bounds__(256) void stats_kernel(const uint16_t* __restrict__ y,
                                                    float* __restrict__ gsum,
                                                    float* __restrict__ gsq){
  constexpr int CP  = C/2;
  constexpr int RSL = 256/CP;
  int t = threadIdx.x;
  int c0 = t % CP, rs = t / CP;
  float s0=0.f,q0=0.f,s1=0.f,q1=0.f;
#pragma unroll 4
  for (int i=0;i<512/RSL;i++){
    int r = blockIdx.x*512 + rs + i*RSL;
    uint32_t u = *(const uint32_t*)(y + (size_t)r*C + 2*c0);
    float v0 = bfu_lo(u), v1 = bfu_hi(u);
    s0 += v0; q0 += v0*v0; s1 += v1; q1 += v1*v1;
  }
  __shared__ float red[4][256];
  red[0][t]=s0; red[1][t]=q0; red[2][t]=s1; red[3][t]=q1;
  __syncthreads();
  if (t < CP){
    float a0=0,a1=0,a2=0,a3=0;
    for (int k=0;k<RSL;k++){
      a0+=red[0][k*CP+t]; a1+=red[1][k*CP+t]; a2+=red[2][k*CP+t]; a3+=red[3][k*CP+t];
    }
    atomicAdd(&gsum[2*t],   a0); atomicAdd(&gsq[2*t],   a1);
    atomicAdd(&gsum[2*t+1], a2); atomicAdd(&gsq[2*t+1], a3);
  }
}

__global__ void finalize_kernel(const float* __restrict__ gsum, const float* __restrict__ gsq,
                                const float* __restrict__ g, const float* __restrict__ be,
                                float* __restrict__ scale, float* __restrict__ shift, int C){
  int c = threadIdx.x;
  if (c >= C) return;
  double mean = (double)gsum[c] / (double)MTOT;
  double var  = (double)gsq[c] / (double)MTOT - mean*mean;
  double s    = (double)g[c] / sqrt(var + 1e-5);
  scale[c] = (float)s;
  shift[c] = (float)((double)be[c] - mean*s);
}

// ---------------- bn3 + relu + maxpool over nsample + transpose ----------------
__global__ __launch_bounds__(256) void maxpool_kernel(const uint16_t* __restrict__ y3,
                                                      const float* __restrict__ scale,
                                                      const float* __restrict__ shift,
                                                      float* __restrict__ out1){
  __shared__ float tr[16][129];
  int t = threadIdx.x;
  int b = blockIdx.x >> 6;
  int s0 = (blockIdx.x & 63) * 16;
  int ch = t & 127, sl0 = t >> 7;
  float scv = scale[ch], shv = shift[ch];
  for (int sl=sl0; sl<16; sl+=2){
    int bs = b*SPTS + s0 + sl;
    const uint16_t* yr = y3 + (size_t)bs*NSAMP*128 + ch;
    float m = 0.0f;
#pragma unroll 4
    for (int k=0;k<NSAMP;k++){
      float v = __uint_as_float(((uint32_t)yr[k*128])<<16);
      float z = fmaxf(fmaf(v, scv, shv), 0.f);
      m = fmaxf(m, z);
    }
    tr[sl][ch] = m;
  }
  __syncthreads();
  int ch2 = t >> 1, hh = t & 1;
  float vals[8];
#pragma unroll
  for (int i=0;i<8;i++) vals[i] = tr[hh*8+i][ch2];
  float* op = out1 + (size_t)b*131072 + (size_t)ch2*1024 + s0 + hh*8;
  float4 v0; v0.x=vals[0]; v0.y=vals[1]; v0.z=vals[2]; v0.w=vals[3];
  float4 v1; v1.x=vals[4]; v1.y=vals[5]; v1.z=vals[6]; v1.w=vals[7];
  *(float4*)op = v0;
  *(float4*)(op+4) = v1;
}

extern "C" void kernel_launch(void* const* d_in, const int* in_sizes, int n_in,
                              void* d_out, int out_size, void* d_ws, size_t ws_size,
                              hipStream_t stream){
  (void)in_sizes; (void)n_in; (void)out_size; (void)ws_size;
  const float* xyz = (const float*)d_in[0];
  const float* pts = (const float*)d_in[1];
  const float* w1 = (const float*)d_in[2];  const float* b1 = (const float*)d_in[3];
  const float* g1 = (const float*)d_in[4];  const float* be1 = (const float*)d_in[5];
  const float* w2 = (const float*)d_in[6];  const float* b2 = (const float*)d_in[7];
  const float* g2 = (const float*)d_in[8];  const float* be2 = (const float*)d_in[9];
  const float* w3 = (const float*)d_in[10]; const float* b3 = (const float*)d_in[11];
  const float* g3 = (const float*)d_in[12]; const float* be3 = (const float*)d_in[13];

  float* out0 = (float*)d_out;                 // (B,3,1024)
  float* out1 = out0 + BATCH*3*SPTS;           // (B,128,1024)

  char* ws = (char*)d_ws;
  float*    ptsT = (float*)(ws + 0);                       // 33,554,432 B
  int*      idx  = (int*)  (ws + 34078720);                //  1,048,576 B
  uint16_t* y1   = (uint16_t*)(ws + 35127296);             // 33,554,432 B
  uint16_t* y2   = (uint16_t*)(ws + 68681728);             // 33,554,432 B
  uint16_t* y3   = (uint16_t*)(ws + 102236160);            // 67,108,864 B
  float*    stats = (float*)(ws + 169345024);              // 1536 floats
  // FPS sorted scratch (float4 x,y,z,orig) lives inside the y1 region
  // (y1 is only written by gemm1, after fps/ball complete): 8*16384*16B = 2 MB.
  float4* sortg = (float4*)(ws + 35127296);
  float* gsum1 = stats;        float* gsq1 = stats + 128;
  float* gsum2 = stats + 256;  float* gsq2 = stats + 384;
  float* gsum3 = stats + 512;  float* gsq3 = stats + 640;
  float* scale1 = stats + 768; float* shift1 = stats + 896;
  float* scale2 = stats + 1024; float* shift2 = stats + 1152;
  float* scale3 = stats + 1280; float* shift3 = stats + 1408;

  hipMemsetAsync(stats, 0, 768*sizeof(float), stream);

  transpose_kernel<<<dim3(NPTS/32, DIMF/32, BATCH), 256, 0, stream>>>(pts, ptsT);
  fps_kernel<<<BATCH, 512, 0, stream>>>(xyz, out0, sortg);
  ball_kernel<<<BATCH*32, 256, 0, stream>>>(xyz, out0, idx);
  gemm1_kernel<<<MTOT/128, 256, 0, stream>>>(xyz, ptsT, idx, out0, w1, b1, y1);
  stats_kernel<64><<<512, 256, 0, stream>>>(y1, gsum1, gsq1);
  finalize_kernel<<<1, 128, 0, stream>>>(gsum1, gsq1, g1, be1, scale1, shift1, 64);
  gemm2_kernel<<<MTOT/128, 256, 0, stream>>>(y1, w2, b2, scale1, shift1, y2);
  stats_kernel<64><<<512, 256, 0, stream>>>(y2, gsum2, gsq2);
  finalize_kernel<<<1, 128, 0, stream>>>(gsum2, gsq2, g2, be2, scale2, shift2, 64);
  gemm3_kernel<<<MTOT/64, 256, 0, stream>>>(y2, w3, b3, scale2, shift2, y3);
  stats_kernel<128><<<512, 256, 0, stream>>>(y3, gsum3, gsq3);
  finalize_kernel<<<1, 128, 0, stream>>>(gsum3, gsq3, g3, be3, scale3, shift3, 128);
  maxpool_kernel<<<BATCH*(SPTS/16), 256, 0, stream>>>(y3, scale3, shift3, out1);
}